// Round 11
// baseline (867.613 us; speedup 1.0000x reference)
//
#include <hip/hip_runtime.h>

#define N_NODES 100000
#define N_EDGES 800000
#define D 128
#define SCAN_N (4 * N_NODES)        // per-relation (dst,mask) buckets
#define SCAN_TOTAL (3 * SCAN_N)     // 1,200,000
#define SCAN_CHUNK 2048             // elems per scan block (256 thr x 8)
#define SCAN_BLOCKS 586             // ceil(1.2M / 2048)
#define SCAN_PAD (SCAN_BLOCKS * SCAN_CHUNK)  // 1,200,128 (pad zeros)

typedef _Float16 f16x8 __attribute__((ext_vector_type(8)));
typedef _Float16 f16x4 __attribute__((ext_vector_type(4)));
typedef float f32x4 __attribute__((ext_vector_type(4)));

#define MFMA_F16(a, b, c) __builtin_amdgcn_mfma_f32_16x16x32_f16((a), (b), (c), 0, 0, 0)

#define CONV_BLOCKS 12500   // N*D/4/256
#define COUNT_BLOCKS 9375   // 3*E/256
#define PREPW_BLOCKS 768    // 3*4*16384/256

// ---- merged prep: conv_x | bucket-count | weight split (disjoint block ranges)
__global__ __launch_bounds__(256) void prep_all(
    const float* __restrict__ x, _Float16* __restrict__ h,
    const int* __restrict__ ei0, const int* __restrict__ ei1, const int* __restrict__ ei2,
    const int* __restrict__ em0, const int* __restrict__ em1, const int* __restrict__ em2,
    int* __restrict__ cnt2, const float* __restrict__ W_l, const float* __restrict__ W_r,
    const float* __restrict__ b_l, _Float16* __restrict__ whi, _Float16* __restrict__ wlo,
    float* __restrict__ bsum) {
    int b = blockIdx.x;
    int tid = threadIdx.x;
    if (b < CONV_BLOCKS) {
        int idx = b * 256 + tid;
        float4 v = reinterpret_cast<const float4*>(x)[idx];
        f16x4 o = {(_Float16)v.x, (_Float16)v.y, (_Float16)v.z, (_Float16)v.w};
        reinterpret_cast<f16x4*>(h)[idx] = o;
    } else if (b < CONV_BLOCKS + COUNT_BLOCKS) {
        int e = (b - CONV_BLOCKS) * 256 + tid;  // [0, 2.4M); r uniform per block
        int r = e / N_EDGES;
        int el = e - r * N_EDGES;
        const int* ei = (r == 0) ? ei0 : (r == 1) ? ei1 : ei2;
        const int* em = (r == 0) ? em0 : (r == 1) ? em1 : em2;
        int dst = ei[N_EDGES + el];
        int m = em[el];
        atomicAdd(&cnt2[(size_t)r * SCAN_N + dst * 4 + m], 1);
    } else {
        int idx = (b - CONV_BLOCKS - COUNT_BLOCKS) * 256 + tid;
        if (idx < 3 * 4 * 16384) {
            int i = idx / (4 * 16384);
            int rem = idx % (4 * 16384);
            int slot = rem / 16384;
            int ok = rem % 16384;
            float v;
            if (slot < 3) {
                v = W_l[(size_t)(i * 3 + slot) * 16384 + ok];
            } else {
                const float* base = W_r + (size_t)i * 3 * 16384;
                v = base[ok] + base[16384 + ok] + base[2 * 16384 + ok];
            }
            _Float16 hi = (_Float16)v;
            whi[idx] = hi;
            wlo[idx] = (_Float16)(v - (float)hi);
        }
        if (idx < 3 * 128) {
            int i = idx / 128, o = idx % 128;
            const float* bb = b_l + (size_t)i * 3 * 128;
            bsum[idx] = bb[o] + bb[128 + o] + bb[256 + o];
        }
    }
}

// ---- device-wide scan, pass 1: per-block sums (block = 2048 elems)
__global__ __launch_bounds__(256) void scan_part(const int* __restrict__ cnt2,
                                                 int* __restrict__ bsums) {
    int tid = threadIdx.x;
    size_t base = (size_t)blockIdx.x * SCAN_CHUNK + tid * 8;
    int4 v0 = *reinterpret_cast<const int4*>(cnt2 + base);
    int4 v1 = *reinterpret_cast<const int4*>(cnt2 + base + 4);
    int s = v0.x + v0.y + v0.z + v0.w + v1.x + v1.y + v1.z + v1.w;
    __shared__ int red[256];
    red[tid] = s;
    __syncthreads();
    for (int off = 128; off > 0; off >>= 1) {
        if (tid < off) red[tid] += red[tid + off];
        __syncthreads();
    }
    if (tid == 0) bsums[blockIdx.x] = red[0];
}

// ---- pass 2: exclusive scan of the 586 block sums (in place), one block
__global__ __launch_bounds__(1024) void scan_tops(int* __restrict__ bsums) {
    __shared__ int s[1024];
    int tid = threadIdx.x;
    int v = (tid < SCAN_BLOCKS) ? bsums[tid] : 0;
    s[tid] = v;
    __syncthreads();
    for (int off = 1; off < 1024; off <<= 1) {
        int x = s[tid];
        int add = (tid >= off) ? s[tid - off] : 0;
        __syncthreads();
        s[tid] = x + add;
        __syncthreads();
    }
    if (tid < SCAN_BLOCKS) bsums[tid] = s[tid] - v;  // exclusive
}

// ---- pass 3: per-block exclusive scan + offset -> bnd (global positions)
__global__ __launch_bounds__(256) void scan_out(const int* __restrict__ cnt2,
                                                const int* __restrict__ bsums,
                                                int* __restrict__ bnd) {
    int tid = threadIdx.x;
    size_t base = (size_t)blockIdx.x * SCAN_CHUNK + tid * 8;
    int4 v0 = *reinterpret_cast<const int4*>(cnt2 + base);
    int4 v1 = *reinterpret_cast<const int4*>(cnt2 + base + 4);
    int l[8] = {v0.x, v0.y, v0.z, v0.w, v1.x, v1.y, v1.z, v1.w};
    int ts = l[0] + l[1] + l[2] + l[3] + l[4] + l[5] + l[6] + l[7];
    __shared__ int s[256];
    s[tid] = ts;
    __syncthreads();
    for (int off = 1; off < 256; off <<= 1) {
        int x = s[tid];
        int add = (tid >= off) ? s[tid - off] : 0;
        __syncthreads();
        s[tid] = x + add;
        __syncthreads();
    }
    int run = bsums[blockIdx.x] + s[tid] - ts;  // exclusive offset for this thread
    int o[8];
#pragma unroll
    for (int j = 0; j < 8; j++) {
        o[j] = run;
        run += l[j];
    }
    int4 o0 = {o[0], o[1], o[2], o[3]};
    int4 o1 = {o[4], o[5], o[6], o[7]};
    *reinterpret_cast<int4*>(bnd + base) = o0;
    *reinterpret_cast<int4*>(bnd + base + 4) = o1;
}

// ---- fill: packed[pos] = src*D at global scan positions, bucketed by (rel,dst,mask)
__global__ __launch_bounds__(256) void fill3(
    const int* __restrict__ ei0, const int* __restrict__ ei1, const int* __restrict__ ei2,
    const int* __restrict__ em0, const int* __restrict__ em1, const int* __restrict__ em2,
    const int* __restrict__ bnd, int* __restrict__ fill2, int* __restrict__ packed) {
    int e = blockIdx.x * 256 + threadIdx.x;  // [0, 2.4M)
    int r = e / N_EDGES;
    int el = e - r * N_EDGES;
    const int* ei = (r == 0) ? ei0 : (r == 1) ? ei1 : ei2;
    const int* em = (r == 0) ? em0 : (r == 1) ? em1 : em2;
    int dst = ei[N_EDGES + el];
    int src = ei[el];
    int m = em[el];
    int gbk = r * SCAN_N + dst * 4 + m;
    int pos = bnd[gbk] + atomicAdd(&fill2[gbk], 1);
    packed[pos] = src * D;  // premultiplied row offset (elements)
}

// ---- fused layer: 3-relation-interleaved gather into LDS, then MFMA GEMM
// block = 256 thr (4 waves) = 32 dst rows x 128 cols; reads h_in, writes h_out/d_out.
__global__ __launch_bounds__(256, 4) void fused_layer(
    const _Float16* __restrict__ h_in, const int* __restrict__ bnd,
    const int* __restrict__ packed, const _Float16* __restrict__ Whi,
    const _Float16* __restrict__ Wlo, const float* __restrict__ bias,
    const int* __restrict__ node_mask, int layer,
    _Float16* __restrict__ h_out, float* __restrict__ out_f32) {
    __shared__ __align__(16) _Float16 smean[3][32][136];  // pitch 272B: aligned, 2-way banks
    int tid = threadIdx.x;
    int wid = tid >> 6;
    int lane = tid & 63;
    int row0 = blockIdx.x * 32;
    int G = (wid << 2) | (lane >> 4);  // group 0..15
    int l = lane & 15;                 // lane in group: owns cols l*8..l*8+7

    // ---- phase 1: group G gathers nodes 2G, 2G+1; the node's 3 relations run as
    // 3 INDEPENDENT load streams interleaved in the instruction stream, so each
    // waitcnt covers 3 chains (idx loads x3 -> row loads x12 -> adds).
    const _Float16* hbase = h_in + l * 8;
#pragma unroll 1
    for (int half = 0; half < 2; half++) {
        int n = (G << 1) | half;
        int bidx = (row0 + n) * 4;
        int beg0 = bnd[bidx], end0 = bnd[bidx + layer + 1];
        int beg1 = bnd[SCAN_N + bidx], end1 = bnd[SCAN_N + bidx + layer + 1];
        int beg2 = bnd[2 * SCAN_N + bidx], end2 = bnd[2 * SCAN_N + bidx + layer + 1];
        int c0 = (beg0 < end0) ? (beg0 & ~3) : end0;
        int c1 = (beg1 < end1) ? (beg1 & ~3) : end1;
        int c2 = (beg2 < end2) ? (beg2 & ~3) : end2;
        int m01 = max(end0 - c0, end1 - c1);
        int nc = (max(m01, end2 - c2) + 3) >> 2;
        f16x8 a0 = (f16x8)(_Float16)0, a1 = (f16x8)(_Float16)0, a2 = (f16x8)(_Float16)0;
#pragma unroll 1
        for (int c = 0; c < nc; c++) {
            int e0 = c0 + 4 * c, e1 = c1 + 4 * c, e2 = c2 + 4 * c;
            bool p0 = e0 < end0, p1 = e1 < end1, p2 = e2 < end2;
            int4 s0, s1, s2;
            // --- issue 3 independent index loads
            if (p0) s0 = *reinterpret_cast<const int4*>(packed + e0);
            if (p1) s1 = *reinterpret_cast<const int4*>(packed + e1);
            if (p2) s2 = *reinterpret_cast<const int4*>(packed + e2);
            // --- issue 12 row loads (4 per relation)
            f16x8 v00, v01, v02, v03, v10, v11, v12, v13, v20, v21, v22, v23;
            if (p0) {
                v00 = *reinterpret_cast<const f16x8*>(hbase + (size_t)(uint)s0.x);
                v01 = *reinterpret_cast<const f16x8*>(hbase + (size_t)(uint)s0.y);
                v02 = *reinterpret_cast<const f16x8*>(hbase + (size_t)(uint)s0.z);
                v03 = *reinterpret_cast<const f16x8*>(hbase + (size_t)(uint)s0.w);
            }
            if (p1) {
                v10 = *reinterpret_cast<const f16x8*>(hbase + (size_t)(uint)s1.x);
                v11 = *reinterpret_cast<const f16x8*>(hbase + (size_t)(uint)s1.y);
                v12 = *reinterpret_cast<const f16x8*>(hbase + (size_t)(uint)s1.z);
                v13 = *reinterpret_cast<const f16x8*>(hbase + (size_t)(uint)s1.w);
            }
            if (p2) {
                v20 = *reinterpret_cast<const f16x8*>(hbase + (size_t)(uint)s2.x);
                v21 = *reinterpret_cast<const f16x8*>(hbase + (size_t)(uint)s2.y);
                v22 = *reinterpret_cast<const f16x8*>(hbase + (size_t)(uint)s2.z);
                v23 = *reinterpret_cast<const f16x8*>(hbase + (size_t)(uint)s2.w);
            }
            // --- accumulate (interior chunk: unconditional tree add)
            if (p0) {
                if (e0 >= beg0 && e0 + 4 <= end0) {
                    a0 += (v00 + v01) + (v02 + v03);
                } else {
                    if (e0 >= beg0 && e0 < end0) a0 += v00;
                    if (e0 + 1 >= beg0 && e0 + 1 < end0) a0 += v01;
                    if (e0 + 2 >= beg0 && e0 + 2 < end0) a0 += v02;
                    if (e0 + 3 >= beg0 && e0 + 3 < end0) a0 += v03;
                }
            }
            if (p1) {
                if (e1 >= beg1 && e1 + 4 <= end1) {
                    a1 += (v10 + v11) + (v12 + v13);
                } else {
                    if (e1 >= beg1 && e1 < end1) a1 += v10;
                    if (e1 + 1 >= beg1 && e1 + 1 < end1) a1 += v11;
                    if (e1 + 2 >= beg1 && e1 + 2 < end1) a1 += v12;
                    if (e1 + 3 >= beg1 && e1 + 3 < end1) a1 += v13;
                }
            }
            if (p2) {
                if (e2 >= beg2 && e2 + 4 <= end2) {
                    a2 += (v20 + v21) + (v22 + v23);
                } else {
                    if (e2 >= beg2 && e2 < end2) a2 += v20;
                    if (e2 + 1 >= beg2 && e2 + 1 < end2) a2 += v21;
                    if (e2 + 2 >= beg2 && e2 + 2 < end2) a2 += v22;
                    if (e2 + 3 >= beg2 && e2 + 3 < end2) a2 += v23;
                }
            }
        }
        float i0 = 1.f / fmaxf((float)(end0 - beg0), 1.f);
        float i1 = 1.f / fmaxf((float)(end1 - beg1), 1.f);
        float i2 = 1.f / fmaxf((float)(end2 - beg2), 1.f);
        f16x8 m0, m1, m2;
#pragma unroll
        for (int k = 0; k < 8; k++) {
            m0[k] = (_Float16)((float)a0[k] * i0);
            m1[k] = (_Float16)((float)a1[k] * i1);
            m2[k] = (_Float16)((float)a2[k] * i2);
        }
        *reinterpret_cast<f16x8*>(&smean[0][n][l * 8]) = m0;
        *reinterpret_cast<f16x8*>(&smean[1][n][l * 8]) = m1;
        *reinterpret_cast<f16x8*>(&smean[2][n][l * 8]) = m2;
    }
    __syncthreads();

    // ---- phase 2: GEMM. wave -> 32 cols; 2x2 16x16 frags; K=128; 2 terms (Whi,Wlo).
    int colbase = wid * 32;
    int ln15 = lane & 15;
    int lg = lane >> 4;
    f32x4 acc[2][2] = {};

#pragma unroll
    for (int p = 0; p < 4; p++) {
        const _Float16* Whp = Whi + (size_t)p * 16384 + (size_t)colbase * D;
        const _Float16* Wlp = Wlo + (size_t)p * 16384 + (size_t)colbase * D;
#pragma unroll
        for (int ks = 0; ks < 4; ks++) {
            int kof = ks * 32 + lg * 8;
            f16x8 a0f, a1f;
            if (p < 3) {
                a0f = *reinterpret_cast<const f16x8*>(&smean[p][ln15][kof]);
                a1f = *reinterpret_cast<const f16x8*>(&smean[p][16 + ln15][kof]);
            } else {
                a0f = *reinterpret_cast<const f16x8*>(h_in + (size_t)(row0 + ln15) * D + kof);
                a1f = *reinterpret_cast<const f16x8*>(h_in + (size_t)(row0 + 16 + ln15) * D + kof);
            }
            f16x8 bh0 = *reinterpret_cast<const f16x8*>(Whp + (size_t)ln15 * D + kof);
            f16x8 bh1 = *reinterpret_cast<const f16x8*>(Whp + (size_t)(16 + ln15) * D + kof);
            f16x8 bl0 = *reinterpret_cast<const f16x8*>(Wlp + (size_t)ln15 * D + kof);
            f16x8 bl1 = *reinterpret_cast<const f16x8*>(Wlp + (size_t)(16 + ln15) * D + kof);
            acc[0][0] = MFMA_F16(a0f, bh0, acc[0][0]);
            acc[0][1] = MFMA_F16(a0f, bh1, acc[0][1]);
            acc[1][0] = MFMA_F16(a1f, bh0, acc[1][0]);
            acc[1][1] = MFMA_F16(a1f, bh1, acc[1][1]);
            acc[0][0] = MFMA_F16(a0f, bl0, acc[0][0]);
            acc[0][1] = MFMA_F16(a0f, bl1, acc[0][1]);
            acc[1][0] = MFMA_F16(a1f, bl0, acc[1][0]);
            acc[1][1] = MFMA_F16(a1f, bl1, acc[1][1]);
        }
    }

    // ---- epilogue: row = row0 + r*16 + lg*4 + j, col = colbase + cc*16 + ln15.
#pragma unroll
    for (int r = 0; r < 2; r++)
#pragma unroll
        for (int j = 0; j < 4; j++) {
            int row = row0 + r * 16 + lg * 4 + j;
            bool valid = node_mask[row] <= layer;
#pragma unroll
            for (int cc = 0; cc < 2; cc++) {
                int col = colbase + cc * 16 + ln15;
                float v = acc[r][cc][j] + bias[col];
                v = valid ? fmaxf(v, 0.f) : 0.f;
                if (out_f32)
                    out_f32[(size_t)row * D + col] = v;
                else
                    h_out[(size_t)row * D + col] = (_Float16)v;
            }
        }
}

extern "C" void kernel_launch(void* const* d_in, const int* in_sizes, int n_in,
                              void* d_out, int out_size, void* d_ws, size_t ws_size,
                              hipStream_t stream) {
    const float* x = (const float*)d_in[0];
    const int* ei0 = (const int*)d_in[1];
    const int* ei1 = (const int*)d_in[2];
    const int* ei2 = (const int*)d_in[3];
    const int* node_mask = (const int*)d_in[4];
    const int* em0 = (const int*)d_in[5];
    const int* em1 = (const int*)d_in[6];
    const int* em2 = (const int*)d_in[7];
    const float* W_l = (const float*)d_in[8];
    const float* b_l = (const float*)d_in[9];
    const float* W_r = (const float*)d_in[10];

    // workspace (~75 MB)
    _Float16* hA = (_Float16*)d_ws;                            // N*D
    _Float16* hB = hA + (size_t)N_NODES * D;                   // N*D
    _Float16* whi = hB + (size_t)N_NODES * D;                  // 3*4*16384
    _Float16* wlo = whi + 3 * 4 * 16384;                       // 3*4*16384
    float* bsum = (float*)(wlo + 3 * 4 * 16384);               // 3*128
    int* cnt2 = (int*)(bsum + 3 * 128);                        // SCAN_PAD (padded, zeroed)
    int* fill2 = cnt2 + SCAN_PAD;                              // SCAN_TOTAL
    int* bsums = fill2 + SCAN_TOTAL;                           // 640 (>= SCAN_BLOCKS)
    int* bnd = bsums + 640;                                    // SCAN_PAD
    int* packed = bnd + SCAN_PAD;                              // 3*E (global positions)

    // zero cnt2 (incl. padding) + fill2 in one contiguous memset
    hipMemsetAsync(cnt2, 0, (size_t)(SCAN_PAD + SCAN_TOTAL) * sizeof(int), stream);

    prep_all<<<CONV_BLOCKS + COUNT_BLOCKS + PREPW_BLOCKS, 256, 0, stream>>>(
        x, hA, ei0, ei1, ei2, em0, em1, em2, cnt2, W_l, W_r, b_l, whi, wlo, bsum);
    scan_part<<<SCAN_BLOCKS, 256, 0, stream>>>(cnt2, bsums);
    scan_tops<<<1, 1024, 0, stream>>>(bsums);
    scan_out<<<SCAN_BLOCKS, 256, 0, stream>>>(cnt2, bsums, bnd);
    fill3<<<COUNT_BLOCKS, 256, 0, stream>>>(ei0, ei1, ei2, em0, em1, em2, bnd, fill2, packed);

    _Float16* hin = hA;
    _Float16* hout = hB;
    for (int i = 0; i < 3; i++) {
        int layer = 3 - i;
        float* of = (i == 2) ? (float*)d_out : nullptr;
        fused_layer<<<N_NODES / 32, 256, 0, stream>>>(
            hin, bnd, packed, whi + (size_t)i * 4 * 16384, wlo + (size_t)i * 4 * 16384,
            bsum + (size_t)i * 128, node_mask, layer, hout, of);
        _Float16* tmp = hin; hin = hout; hout = tmp;
    }
}

// Round 12
// 711.146 us; speedup vs baseline: 1.2200x; 1.2200x over previous
//
#include <hip/hip_runtime.h>

#define N_NODES 100000
#define N_EDGES 800000
#define D 128
#define SCAN_N (4 * N_NODES)        // per-relation (dst,mask) buckets
#define SCAN_TOTAL (3 * SCAN_N)     // 1,200,000
#define SCAN_CHUNK 2048             // elems per scan block (256 thr x 8)
#define SCAN_BLOCKS 586             // ceil(1.2M / 2048)
#define SCAN_PAD (SCAN_BLOCKS * SCAN_CHUNK)  // 1,200,128 (pad zeros)

typedef _Float16 f16x8 __attribute__((ext_vector_type(8)));
typedef _Float16 f16x4 __attribute__((ext_vector_type(4)));
typedef float f32x4 __attribute__((ext_vector_type(4)));

#define MFMA_F16(a, b, c) __builtin_amdgcn_mfma_f32_16x16x32_f16((a), (b), (c), 0, 0, 0)

#define CONV_BLOCKS 12500   // N*D/4/256
#define COUNT_BLOCKS 9375   // 3*E/256
#define PREPW_BLOCKS 768    // 3*4*16384/256

// ---- merged prep: conv_x | bucket-count | weight fp16 (disjoint block ranges)
__global__ __launch_bounds__(256) void prep_all(
    const float* __restrict__ x, _Float16* __restrict__ h,
    const int* __restrict__ ei0, const int* __restrict__ ei1, const int* __restrict__ ei2,
    const int* __restrict__ em0, const int* __restrict__ em1, const int* __restrict__ em2,
    int* __restrict__ cnt2, const float* __restrict__ W_l, const float* __restrict__ W_r,
    const float* __restrict__ b_l, _Float16* __restrict__ whi, float* __restrict__ bsum) {
    int b = blockIdx.x;
    int tid = threadIdx.x;
    if (b < CONV_BLOCKS) {
        int idx = b * 256 + tid;
        float4 v = reinterpret_cast<const float4*>(x)[idx];
        f16x4 o = {(_Float16)v.x, (_Float16)v.y, (_Float16)v.z, (_Float16)v.w};
        reinterpret_cast<f16x4*>(h)[idx] = o;
    } else if (b < CONV_BLOCKS + COUNT_BLOCKS) {
        int e = (b - CONV_BLOCKS) * 256 + tid;  // [0, 2.4M); r uniform per block
        int r = e / N_EDGES;
        int el = e - r * N_EDGES;
        const int* ei = (r == 0) ? ei0 : (r == 1) ? ei1 : ei2;
        const int* em = (r == 0) ? em0 : (r == 1) ? em1 : em2;
        int dst = ei[N_EDGES + el];
        int m = em[el];
        atomicAdd(&cnt2[(size_t)r * SCAN_N + dst * 4 + m], 1);
    } else {
        int idx = (b - CONV_BLOCKS - COUNT_BLOCKS) * 256 + tid;
        if (idx < 3 * 4 * 16384) {
            int i = idx / (4 * 16384);
            int rem = idx % (4 * 16384);
            int slot = rem / 16384;
            int ok = rem % 16384;
            float v;
            if (slot < 3) {
                v = W_l[(size_t)(i * 3 + slot) * 16384 + ok];
            } else {
                const float* base = W_r + (size_t)i * 3 * 16384;
                v = base[ok] + base[16384 + ok] + base[2 * 16384 + ok];
            }
            whi[idx] = (_Float16)v;
        }
        if (idx < 3 * 128) {
            int i = idx / 128, o = idx % 128;
            const float* bb = b_l + (size_t)i * 3 * 128;
            bsum[idx] = bb[o] + bb[128 + o] + bb[256 + o];
        }
    }
}

// ---- device-wide scan, pass 1: per-block sums (block = 2048 elems)
__global__ __launch_bounds__(256) void scan_part(const int* __restrict__ cnt2,
                                                 int* __restrict__ bsums) {
    int tid = threadIdx.x;
    size_t base = (size_t)blockIdx.x * SCAN_CHUNK + tid * 8;
    int4 v0 = *reinterpret_cast<const int4*>(cnt2 + base);
    int4 v1 = *reinterpret_cast<const int4*>(cnt2 + base + 4);
    int s = v0.x + v0.y + v0.z + v0.w + v1.x + v1.y + v1.z + v1.w;
    __shared__ int red[256];
    red[tid] = s;
    __syncthreads();
    for (int off = 128; off > 0; off >>= 1) {
        if (tid < off) red[tid] += red[tid + off];
        __syncthreads();
    }
    if (tid == 0) bsums[blockIdx.x] = red[0];
}

// ---- pass 2: exclusive scan of the 586 block sums (in place), one block
__global__ __launch_bounds__(1024) void scan_tops(int* __restrict__ bsums) {
    __shared__ int s[1024];
    int tid = threadIdx.x;
    int v = (tid < SCAN_BLOCKS) ? bsums[tid] : 0;
    s[tid] = v;
    __syncthreads();
    for (int off = 1; off < 1024; off <<= 1) {
        int x = s[tid];
        int add = (tid >= off) ? s[tid - off] : 0;
        __syncthreads();
        s[tid] = x + add;
        __syncthreads();
    }
    if (tid < SCAN_BLOCKS) bsums[tid] = s[tid] - v;  // exclusive
}

// ---- pass 3: per-block exclusive scan + offset -> bnd (global positions)
__global__ __launch_bounds__(256) void scan_out(const int* __restrict__ cnt2,
                                                const int* __restrict__ bsums,
                                                int* __restrict__ bnd) {
    int tid = threadIdx.x;
    size_t base = (size_t)blockIdx.x * SCAN_CHUNK + tid * 8;
    int4 v0 = *reinterpret_cast<const int4*>(cnt2 + base);
    int4 v1 = *reinterpret_cast<const int4*>(cnt2 + base + 4);
    int l[8] = {v0.x, v0.y, v0.z, v0.w, v1.x, v1.y, v1.z, v1.w};
    int ts = l[0] + l[1] + l[2] + l[3] + l[4] + l[5] + l[6] + l[7];
    __shared__ int s[256];
    s[tid] = ts;
    __syncthreads();
    for (int off = 1; off < 256; off <<= 1) {
        int x = s[tid];
        int add = (tid >= off) ? s[tid - off] : 0;
        __syncthreads();
        s[tid] = x + add;
        __syncthreads();
    }
    int run = bsums[blockIdx.x] + s[tid] - ts;  // exclusive offset for this thread
    int o[8];
#pragma unroll
    for (int j = 0; j < 8; j++) {
        o[j] = run;
        run += l[j];
    }
    int4 o0 = {o[0], o[1], o[2], o[3]};
    int4 o1 = {o[4], o[5], o[6], o[7]};
    *reinterpret_cast<int4*>(bnd + base) = o0;
    *reinterpret_cast<int4*>(bnd + base + 4) = o1;
}

// ---- fill: packed[pos] = src*D at global scan positions, bucketed by (rel,dst,mask)
__global__ __launch_bounds__(256) void fill3(
    const int* __restrict__ ei0, const int* __restrict__ ei1, const int* __restrict__ ei2,
    const int* __restrict__ em0, const int* __restrict__ em1, const int* __restrict__ em2,
    const int* __restrict__ bnd, int* __restrict__ fill2, int* __restrict__ packed) {
    int e = blockIdx.x * 256 + threadIdx.x;  // [0, 2.4M)
    int r = e / N_EDGES;
    int el = e - r * N_EDGES;
    const int* ei = (r == 0) ? ei0 : (r == 1) ? ei1 : ei2;
    const int* em = (r == 0) ? em0 : (r == 1) ? em1 : em2;
    int dst = ei[N_EDGES + el];
    int src = ei[el];
    int m = em[el];
    int gbk = r * SCAN_N + dst * 4 + m;
    int pos = bnd[gbk] + atomicAdd(&fill2[gbk], 1);
    packed[pos] = src * D;  // premultiplied row offset (elements)
}

// ---- fused layer: packed-fp16 gather into LDS, then MFMA GEMM (single fp16 W)
// block = 256 thr (4 waves) = 32 dst rows x 128 cols; reads h_in, writes h_out/d_out.
__global__ __launch_bounds__(256, 4) void fused_layer(
    const _Float16* __restrict__ h_in, const int* __restrict__ bnd,
    const int* __restrict__ packed, const _Float16* __restrict__ Whi,
    const float* __restrict__ bias, const int* __restrict__ node_mask, int layer,
    _Float16* __restrict__ h_out, float* __restrict__ out_f32) {
    __shared__ __align__(16) _Float16 smean[3][32][136];  // pitch 272B: aligned, 2-way banks
    int tid = threadIdx.x;
    int wid = tid >> 6;
    int lane = tid & 63;
    int row0 = blockIdx.x * 32;
    int g = lane >> 4;  // task group 0..3
    int l = lane & 15;  // lane in group: owns cols l*8..l*8+7

    // ---- phase 1: 96 (rel,node) tasks; wave runs 4 concurrent groups x 6 iters.
    // Per 4-edge chunk: ONE aligned int4 index load (group-uniform) + 4 independent
    // row loads + 4x4 v_pk_add_f16.
    const _Float16* hbase = h_in + l * 8;
#pragma unroll 1
    for (int it = 0; it < 6; it++) {
        int t = wid * 24 + it * 4 + g;
        int r = t >> 5;
        int n = t & 31;
        const int* B = bnd + (size_t)r * SCAN_N + (row0 + n) * 4;
        int beg = B[0];
        int end = B[layer + 1];  // prefix: all edges with mask <= layer
        int deg = end - beg;
        f16x8 acc = (f16x8)(_Float16)0;
#pragma unroll 1
        for (int e4 = beg & ~3; e4 < end; e4 += 4) {
            int4 s4 = *reinterpret_cast<const int4*>(packed + e4);  // 16B-aligned, uniform in group
            if (e4 >= beg && e4 + 4 <= end) {  // interior chunk: all 4 valid (uniform branch)
                f16x8 v0 = *reinterpret_cast<const f16x8*>(hbase + (size_t)(uint)s4.x);
                f16x8 v1 = *reinterpret_cast<const f16x8*>(hbase + (size_t)(uint)s4.y);
                f16x8 v2 = *reinterpret_cast<const f16x8*>(hbase + (size_t)(uint)s4.z);
                f16x8 v3 = *reinterpret_cast<const f16x8*>(hbase + (size_t)(uint)s4.w);
                acc += v0;
                acc += v1;
                acc += v2;
                acc += v3;
            } else {  // boundary chunk (<=2 per task)
                int ss[4] = {s4.x, s4.y, s4.z, s4.w};
#pragma unroll
                for (int j = 0; j < 4; j++) {
                    int e = e4 + j;
                    if (e >= beg && e < end)
                        acc += *reinterpret_cast<const f16x8*>(hbase + (size_t)(uint)ss[j]);
                }
            }
        }
        float inv = 1.f / fmaxf((float)deg, 1.f);
        f16x8 mv;
#pragma unroll
        for (int k = 0; k < 8; k++) mv[k] = (_Float16)((float)acc[k] * inv);
        *reinterpret_cast<f16x8*>(&smean[r][n][l * 8]) = mv;
    }
    __syncthreads();

    // ---- phase 2: GEMM. wave -> 32 cols; 2x2 16x16 frags; K=128; single fp16 W term.
    int colbase = wid * 32;
    int ln15 = lane & 15;
    int lg = lane >> 4;
    f32x4 acc[2][2] = {};

#pragma unroll
    for (int p = 0; p < 4; p++) {
        const _Float16* Whp = Whi + (size_t)p * 16384 + (size_t)colbase * D;
#pragma unroll
        for (int ks = 0; ks < 4; ks++) {
            int kof = ks * 32 + lg * 8;
            f16x8 a0f, a1f;
            if (p < 3) {
                a0f = *reinterpret_cast<const f16x8*>(&smean[p][ln15][kof]);
                a1f = *reinterpret_cast<const f16x8*>(&smean[p][16 + ln15][kof]);
            } else {
                a0f = *reinterpret_cast<const f16x8*>(h_in + (size_t)(row0 + ln15) * D + kof);
                a1f = *reinterpret_cast<const f16x8*>(h_in + (size_t)(row0 + 16 + ln15) * D + kof);
            }
            f16x8 bh0 = *reinterpret_cast<const f16x8*>(Whp + (size_t)ln15 * D + kof);
            f16x8 bh1 = *reinterpret_cast<const f16x8*>(Whp + (size_t)(16 + ln15) * D + kof);
            acc[0][0] = MFMA_F16(a0f, bh0, acc[0][0]);
            acc[0][1] = MFMA_F16(a0f, bh1, acc[0][1]);
            acc[1][0] = MFMA_F16(a1f, bh0, acc[1][0]);
            acc[1][1] = MFMA_F16(a1f, bh1, acc[1][1]);
        }
    }

    // ---- epilogue: row = row0 + r*16 + lg*4 + j, col = colbase + cc*16 + ln15.
#pragma unroll
    for (int r = 0; r < 2; r++)
#pragma unroll
        for (int j = 0; j < 4; j++) {
            int row = row0 + r * 16 + lg * 4 + j;
            bool valid = node_mask[row] <= layer;
#pragma unroll
            for (int cc = 0; cc < 2; cc++) {
                int col = colbase + cc * 16 + ln15;
                float v = acc[r][cc][j] + bias[col];
                v = valid ? fmaxf(v, 0.f) : 0.f;
                if (out_f32)
                    out_f32[(size_t)row * D + col] = v;
                else
                    h_out[(size_t)row * D + col] = (_Float16)v;
            }
        }
}

extern "C" void kernel_launch(void* const* d_in, const int* in_sizes, int n_in,
                              void* d_out, int out_size, void* d_ws, size_t ws_size,
                              hipStream_t stream) {
    const float* x = (const float*)d_in[0];
    const int* ei0 = (const int*)d_in[1];
    const int* ei1 = (const int*)d_in[2];
    const int* ei2 = (const int*)d_in[3];
    const int* node_mask = (const int*)d_in[4];
    const int* em0 = (const int*)d_in[5];
    const int* em1 = (const int*)d_in[6];
    const int* em2 = (const int*)d_in[7];
    const float* W_l = (const float*)d_in[8];
    const float* b_l = (const float*)d_in[9];
    const float* W_r = (const float*)d_in[10];

    // workspace (~75 MB)
    _Float16* hA = (_Float16*)d_ws;                            // N*D
    _Float16* hB = hA + (size_t)N_NODES * D;                   // N*D
    _Float16* whi = hB + (size_t)N_NODES * D;                  // 3*4*16384
    float* bsum = (float*)(whi + 3 * 4 * 16384);               // 3*128
    int* cnt2 = (int*)(bsum + 3 * 128);                        // SCAN_PAD (padded, zeroed)
    int* fill2 = cnt2 + SCAN_PAD;                              // SCAN_TOTAL
    int* bsums = fill2 + SCAN_TOTAL;                           // 640 (>= SCAN_BLOCKS)
    int* bnd = bsums + 640;                                    // SCAN_PAD
    int* packed = bnd + SCAN_PAD;                              // 3*E (global positions)

    // zero cnt2 (incl. padding) + fill2 in one contiguous memset
    hipMemsetAsync(cnt2, 0, (size_t)(SCAN_PAD + SCAN_TOTAL) * sizeof(int), stream);

    prep_all<<<CONV_BLOCKS + COUNT_BLOCKS + PREPW_BLOCKS, 256, 0, stream>>>(
        x, hA, ei0, ei1, ei2, em0, em1, em2, cnt2, W_l, W_r, b_l, whi, bsum);
    scan_part<<<SCAN_BLOCKS, 256, 0, stream>>>(cnt2, bsums);
    scan_tops<<<1, 1024, 0, stream>>>(bsums);
    scan_out<<<SCAN_BLOCKS, 256, 0, stream>>>(cnt2, bsums, bnd);
    fill3<<<COUNT_BLOCKS, 256, 0, stream>>>(ei0, ei1, ei2, em0, em1, em2, bnd, fill2, packed);

    _Float16* hin = hA;
    _Float16* hout = hB;
    for (int i = 0; i < 3; i++) {
        int layer = 3 - i;
        float* of = (i == 2) ? (float*)d_out : nullptr;
        fused_layer<<<N_NODES / 32, 256, 0, stream>>>(
            hin, bnd, packed, whi + (size_t)i * 4 * 16384,
            bsum + (size_t)i * 128, node_mask, layer, hout, of);
        _Float16* tmp = hin; hin = hout; hout = tmp;
    }
}

// Round 13
// 676.921 us; speedup vs baseline: 1.2817x; 1.0506x over previous
//
#include <hip/hip_runtime.h>

#define N_NODES 100000
#define N_EDGES 800000
#define D 128
#define SCAN_N (4 * N_NODES)        // per-relation (dst,mask) buckets
#define SCAN_TOTAL (3 * SCAN_N)     // 1,200,000
#define SCAN_CHUNK 2048             // elems per scan block (256 thr x 8)
#define SCAN_BLOCKS 586             // ceil(1.2M / 2048)
#define SCAN_PAD (SCAN_BLOCKS * SCAN_CHUNK)  // 1,200,128 (pad zeros)

typedef _Float16 f16x8 __attribute__((ext_vector_type(8)));
typedef _Float16 f16x4 __attribute__((ext_vector_type(4)));
typedef float f32x4 __attribute__((ext_vector_type(4)));

#define MFMA_F16(a, b, c) __builtin_amdgcn_mfma_f32_16x16x32_f16((a), (b), (c), 0, 0, 0)

#define CONV_BLOCKS 12500   // N*D/4/256
#define COUNT_BLOCKS 9375   // 3*E/256
#define PREPW_BLOCKS 768    // 3*4*16384/256

// ---- merged prep: conv_x | bucket-count | weight fp16 (disjoint block ranges)
__global__ __launch_bounds__(256) void prep_all(
    const float* __restrict__ x, _Float16* __restrict__ h,
    const int* __restrict__ ei0, const int* __restrict__ ei1, const int* __restrict__ ei2,
    const int* __restrict__ em0, const int* __restrict__ em1, const int* __restrict__ em2,
    int* __restrict__ cnt2, const float* __restrict__ W_l, const float* __restrict__ W_r,
    const float* __restrict__ b_l, _Float16* __restrict__ whi, float* __restrict__ bsum) {
    int b = blockIdx.x;
    int tid = threadIdx.x;
    if (b < CONV_BLOCKS) {
        int idx = b * 256 + tid;
        float4 v = reinterpret_cast<const float4*>(x)[idx];
        f16x4 o = {(_Float16)v.x, (_Float16)v.y, (_Float16)v.z, (_Float16)v.w};
        reinterpret_cast<f16x4*>(h)[idx] = o;
    } else if (b < CONV_BLOCKS + COUNT_BLOCKS) {
        int e = (b - CONV_BLOCKS) * 256 + tid;  // [0, 2.4M); r uniform per block
        int r = e / N_EDGES;
        int el = e - r * N_EDGES;
        const int* ei = (r == 0) ? ei0 : (r == 1) ? ei1 : ei2;
        const int* em = (r == 0) ? em0 : (r == 1) ? em1 : em2;
        int dst = ei[N_EDGES + el];
        int m = em[el];
        atomicAdd(&cnt2[(size_t)r * SCAN_N + dst * 4 + m], 1);
    } else {
        int idx = (b - CONV_BLOCKS - COUNT_BLOCKS) * 256 + tid;
        if (idx < 3 * 4 * 16384) {
            int i = idx / (4 * 16384);
            int rem = idx % (4 * 16384);
            int slot = rem / 16384;
            int ok = rem % 16384;
            float v;
            if (slot < 3) {
                v = W_l[(size_t)(i * 3 + slot) * 16384 + ok];
            } else {
                const float* base = W_r + (size_t)i * 3 * 16384;
                v = base[ok] + base[16384 + ok] + base[2 * 16384 + ok];
            }
            whi[idx] = (_Float16)v;
        }
        if (idx < 3 * 128) {
            int i = idx / 128, o = idx % 128;
            const float* bb = b_l + (size_t)i * 3 * 128;
            bsum[idx] = bb[o] + bb[128 + o] + bb[256 + o];
        }
    }
}

// ---- device-wide scan, pass 1: per-block sums (block = 2048 elems)
__global__ __launch_bounds__(256) void scan_part(const int* __restrict__ cnt2,
                                                 int* __restrict__ bsums) {
    int tid = threadIdx.x;
    size_t base = (size_t)blockIdx.x * SCAN_CHUNK + tid * 8;
    int4 v0 = *reinterpret_cast<const int4*>(cnt2 + base);
    int4 v1 = *reinterpret_cast<const int4*>(cnt2 + base + 4);
    int s = v0.x + v0.y + v0.z + v0.w + v1.x + v1.y + v1.z + v1.w;
    __shared__ int red[256];
    red[tid] = s;
    __syncthreads();
    for (int off = 128; off > 0; off >>= 1) {
        if (tid < off) red[tid] += red[tid + off];
        __syncthreads();
    }
    if (tid == 0) bsums[blockIdx.x] = red[0];
}

// ---- pass 2: exclusive scan of the 586 block sums (in place), one block
__global__ __launch_bounds__(1024) void scan_tops(int* __restrict__ bsums) {
    __shared__ int s[1024];
    int tid = threadIdx.x;
    int v = (tid < SCAN_BLOCKS) ? bsums[tid] : 0;
    s[tid] = v;
    __syncthreads();
    for (int off = 1; off < 1024; off <<= 1) {
        int x = s[tid];
        int add = (tid >= off) ? s[tid - off] : 0;
        __syncthreads();
        s[tid] = x + add;
        __syncthreads();
    }
    if (tid < SCAN_BLOCKS) bsums[tid] = s[tid] - v;  // exclusive
}

// ---- pass 3: per-block exclusive scan + offset -> bnd (global positions)
__global__ __launch_bounds__(256) void scan_out(const int* __restrict__ cnt2,
                                                const int* __restrict__ bsums,
                                                int* __restrict__ bnd) {
    int tid = threadIdx.x;
    size_t base = (size_t)blockIdx.x * SCAN_CHUNK + tid * 8;
    int4 v0 = *reinterpret_cast<const int4*>(cnt2 + base);
    int4 v1 = *reinterpret_cast<const int4*>(cnt2 + base + 4);
    int l[8] = {v0.x, v0.y, v0.z, v0.w, v1.x, v1.y, v1.z, v1.w};
    int ts = l[0] + l[1] + l[2] + l[3] + l[4] + l[5] + l[6] + l[7];
    __shared__ int s[256];
    s[tid] = ts;
    __syncthreads();
    for (int off = 1; off < 256; off <<= 1) {
        int x = s[tid];
        int add = (tid >= off) ? s[tid - off] : 0;
        __syncthreads();
        s[tid] = x + add;
        __syncthreads();
    }
    int run = bsums[blockIdx.x] + s[tid] - ts;  // exclusive offset for this thread
    int o[8];
#pragma unroll
    for (int j = 0; j < 8; j++) {
        o[j] = run;
        run += l[j];
    }
    int4 o0 = {o[0], o[1], o[2], o[3]};
    int4 o1 = {o[4], o[5], o[6], o[7]};
    *reinterpret_cast<int4*>(bnd + base) = o0;
    *reinterpret_cast<int4*>(bnd + base + 4) = o1;
}

// ---- fill: packed[pos] = src*D at global scan positions, bucketed by (rel,dst,mask)
__global__ __launch_bounds__(256) void fill3(
    const int* __restrict__ ei0, const int* __restrict__ ei1, const int* __restrict__ ei2,
    const int* __restrict__ em0, const int* __restrict__ em1, const int* __restrict__ em2,
    const int* __restrict__ bnd, int* __restrict__ fill2, int* __restrict__ packed) {
    int e = blockIdx.x * 256 + threadIdx.x;  // [0, 2.4M)
    int r = e / N_EDGES;
    int el = e - r * N_EDGES;
    const int* ei = (r == 0) ? ei0 : (r == 1) ? ei1 : ei2;
    const int* em = (r == 0) ? em0 : (r == 1) ? em1 : em2;
    int dst = ei[N_EDGES + el];
    int src = ei[el];
    int m = em[el];
    int gbk = r * SCAN_N + dst * 4 + m;
    int pos = bnd[gbk] + atomicAdd(&fill2[gbk], 1);
    packed[pos] = src * D;  // premultiplied row offset (elements)
}

// ---- fused layer: validity-skipped, 2-deep-pipelined gather + MFMA GEMM
// block = 256 thr (4 waves) = 32 dst rows x 128 cols; reads h_in, writes h_out/d_out.
__global__ __launch_bounds__(256, 4) void fused_layer(
    const _Float16* __restrict__ h_in, const int* __restrict__ bnd,
    const int* __restrict__ packed, const _Float16* __restrict__ Whi,
    const float* __restrict__ bias, const int* __restrict__ node_mask, int layer,
    _Float16* __restrict__ h_out, float* __restrict__ out_f32) {
    __shared__ __align__(16) _Float16 smean[3][32][136];  // pitch 272B: aligned, 2-way banks
    int tid = threadIdx.x;
    int wid = tid >> 6;
    int lane = tid & 63;
    int row0 = blockIdx.x * 32;

    // ---- block-level early-out: node_mask sorted; if first row invalid, all 32 are.
    if (node_mask[row0] > layer) {
        if (out_f32) {
            f32x4 z = {0.f, 0.f, 0.f, 0.f};
            f32x4* o = reinterpret_cast<f32x4*>(out_f32 + (size_t)row0 * D);
#pragma unroll
            for (int k = 0; k < 4; k++) o[tid + k * 256] = z;
        } else {
            f16x8 z = (f16x8)(_Float16)0;
            f16x8* o = reinterpret_cast<f16x8*>(h_out + (size_t)row0 * D);
#pragma unroll
            for (int k = 0; k < 2; k++) o[tid + k * 256] = z;
        }
        return;
    }

    int g = lane >> 4;  // task group 0..3
    int l = lane & 15;  // lane in group: owns cols l*8..l*8+7

    // ---- phase 1: 96 (rel,node) tasks; wave runs 4 concurrent groups x 6 iters.
    // Valid tasks gather with a 2-deep register pipeline: chunk c+1's index+rows
    // are issued BEFORE accumulating chunk c's rows (one stream -> L2 locality kept).
    const _Float16* hbase = h_in + l * 8;
#pragma unroll 1
    for (int it = 0; it < 6; it++) {
        int t = wid * 24 + it * 4 + g;
        int r = t >> 5;
        int n = t & 31;
        if (node_mask[row0 + n] > layer) continue;  // output row forced 0; skip gather
        const int* B = bnd + (size_t)r * SCAN_N + (row0 + n) * 4;
        int beg = B[0];
        int end = B[layer + 1];  // prefix: all edges with mask <= layer
        int deg = end - beg;
        f16x8 acc = (f16x8)(_Float16)0;
        int abeg = (beg + 3) & ~3;
        int aend = end & ~3;
        if (abeg >= aend) {  // tiny degree: all scalar
            for (int e = beg; e < end; e++)
                acc += *reinterpret_cast<const f16x8*>(hbase + (size_t)(uint)packed[e]);
        } else {
            for (int e = beg; e < abeg; e++)  // lead-in (<=3)
                acc += *reinterpret_cast<const f16x8*>(hbase + (size_t)(uint)packed[e]);
            // pipelined full chunks
            int4 s = *reinterpret_cast<const int4*>(packed + abeg);
            f16x8 r0 = *reinterpret_cast<const f16x8*>(hbase + (size_t)(uint)s.x);
            f16x8 r1 = *reinterpret_cast<const f16x8*>(hbase + (size_t)(uint)s.y);
            f16x8 r2 = *reinterpret_cast<const f16x8*>(hbase + (size_t)(uint)s.z);
            f16x8 r3 = *reinterpret_cast<const f16x8*>(hbase + (size_t)(uint)s.w);
#pragma unroll 1
            for (int e4 = abeg + 4; e4 < aend; e4 += 4) {
                int4 sn = *reinterpret_cast<const int4*>(packed + e4);
                f16x8 n0 = *reinterpret_cast<const f16x8*>(hbase + (size_t)(uint)sn.x);
                f16x8 n1 = *reinterpret_cast<const f16x8*>(hbase + (size_t)(uint)sn.y);
                f16x8 n2 = *reinterpret_cast<const f16x8*>(hbase + (size_t)(uint)sn.z);
                f16x8 n3 = *reinterpret_cast<const f16x8*>(hbase + (size_t)(uint)sn.w);
                acc += (r0 + r1) + (r2 + r3);  // waits only on r*, n* stay in flight
                r0 = n0; r1 = n1; r2 = n2; r3 = n3;
            }
            acc += (r0 + r1) + (r2 + r3);
            for (int e = aend; e < end; e++)  // tail (<=3)
                acc += *reinterpret_cast<const f16x8*>(hbase + (size_t)(uint)packed[e]);
        }
        float inv = 1.f / fmaxf((float)deg, 1.f);
        f16x8 mv;
#pragma unroll
        for (int k = 0; k < 8; k++) mv[k] = (_Float16)((float)acc[k] * inv);
        *reinterpret_cast<f16x8*>(&smean[r][n][l * 8]) = mv;
    }
    __syncthreads();

    // ---- phase 2: GEMM. wave -> 32 cols; 2x2 16x16 frags; K=128; single fp16 W term.
    // Skipped tasks leave garbage in their smean rows: harmless, since MFMA C-row r
    // depends only on A-row r, and invalid rows are forced to 0 in the epilogue.
    int colbase = wid * 32;
    int ln15 = lane & 15;
    int lg = lane >> 4;
    f32x4 acc[2][2] = {};

#pragma unroll
    for (int p = 0; p < 4; p++) {
        const _Float16* Whp = Whi + (size_t)p * 16384 + (size_t)colbase * D;
#pragma unroll
        for (int ks = 0; ks < 4; ks++) {
            int kof = ks * 32 + lg * 8;
            f16x8 a0f, a1f;
            if (p < 3) {
                a0f = *reinterpret_cast<const f16x8*>(&smean[p][ln15][kof]);
                a1f = *reinterpret_cast<const f16x8*>(&smean[p][16 + ln15][kof]);
            } else {
                a0f = *reinterpret_cast<const f16x8*>(h_in + (size_t)(row0 + ln15) * D + kof);
                a1f = *reinterpret_cast<const f16x8*>(h_in + (size_t)(row0 + 16 + ln15) * D + kof);
            }
            f16x8 bh0 = *reinterpret_cast<const f16x8*>(Whp + (size_t)ln15 * D + kof);
            f16x8 bh1 = *reinterpret_cast<const f16x8*>(Whp + (size_t)(16 + ln15) * D + kof);
            acc[0][0] = MFMA_F16(a0f, bh0, acc[0][0]);
            acc[0][1] = MFMA_F16(a0f, bh1, acc[0][1]);
            acc[1][0] = MFMA_F16(a1f, bh0, acc[1][0]);
            acc[1][1] = MFMA_F16(a1f, bh1, acc[1][1]);
        }
    }

    // ---- epilogue: row = row0 + r*16 + lg*4 + j, col = colbase + cc*16 + ln15.
#pragma unroll
    for (int r = 0; r < 2; r++)
#pragma unroll
        for (int j = 0; j < 4; j++) {
            int row = row0 + r * 16 + lg * 4 + j;
            bool valid = node_mask[row] <= layer;
#pragma unroll
            for (int cc = 0; cc < 2; cc++) {
                int col = colbase + cc * 16 + ln15;
                float v = acc[r][cc][j] + bias[col];
                v = valid ? fmaxf(v, 0.f) : 0.f;
                if (out_f32)
                    out_f32[(size_t)row * D + col] = v;
                else
                    h_out[(size_t)row * D + col] = (_Float16)v;
            }
        }
}

extern "C" void kernel_launch(void* const* d_in, const int* in_sizes, int n_in,
                              void* d_out, int out_size, void* d_ws, size_t ws_size,
                              hipStream_t stream) {
    const float* x = (const float*)d_in[0];
    const int* ei0 = (const int*)d_in[1];
    const int* ei1 = (const int*)d_in[2];
    const int* ei2 = (const int*)d_in[3];
    const int* node_mask = (const int*)d_in[4];
    const int* em0 = (const int*)d_in[5];
    const int* em1 = (const int*)d_in[6];
    const int* em2 = (const int*)d_in[7];
    const float* W_l = (const float*)d_in[8];
    const float* b_l = (const float*)d_in[9];
    const float* W_r = (const float*)d_in[10];

    // workspace (~75 MB)
    _Float16* hA = (_Float16*)d_ws;                            // N*D
    _Float16* hB = hA + (size_t)N_NODES * D;                   // N*D
    _Float16* whi = hB + (size_t)N_NODES * D;                  // 3*4*16384
    float* bsum = (float*)(whi + 3 * 4 * 16384);               // 3*128
    int* cnt2 = (int*)(bsum + 3 * 128);                        // SCAN_PAD (padded, zeroed)
    int* fill2 = cnt2 + SCAN_PAD;                              // SCAN_TOTAL
    int* bsums = fill2 + SCAN_TOTAL;                           // 640 (>= SCAN_BLOCKS)
    int* bnd = bsums + 640;                                    // SCAN_PAD
    int* packed = bnd + SCAN_PAD;                              // 3*E (global positions)

    // zero cnt2 (incl. padding) + fill2 in one contiguous memset
    hipMemsetAsync(cnt2, 0, (size_t)(SCAN_PAD + SCAN_TOTAL) * sizeof(int), stream);

    prep_all<<<CONV_BLOCKS + COUNT_BLOCKS + PREPW_BLOCKS, 256, 0, stream>>>(
        x, hA, ei0, ei1, ei2, em0, em1, em2, cnt2, W_l, W_r, b_l, whi, bsum);
    scan_part<<<SCAN_BLOCKS, 256, 0, stream>>>(cnt2, bsums);
    scan_tops<<<1, 1024, 0, stream>>>(bsums);
    scan_out<<<SCAN_BLOCKS, 256, 0, stream>>>(cnt2, bsums, bnd);
    fill3<<<COUNT_BLOCKS, 256, 0, stream>>>(ei0, ei1, ei2, em0, em1, em2, bnd, fill2, packed);

    _Float16* hin = hA;
    _Float16* hout = hB;
    for (int i = 0; i < 3; i++) {
        int layer = 3 - i;
        float* of = (i == 2) ? (float*)d_out : nullptr;
        fused_layer<<<N_NODES / 32, 256, 0, stream>>>(
            hin, bnd, packed, whi + (size_t)i * 4 * 16384,
            bsum + (size_t)i * 128, node_mask, layer, hout, of);
        _Float16* tmp = hin; hin = hout; hout = tmp;
    }
}

// Round 14
// 631.404 us; speedup vs baseline: 1.3741x; 1.0721x over previous
//
#include <hip/hip_runtime.h>

#define N_NODES 100000
#define N_EDGES 800000
#define D 128
#define SCAN_N (4 * N_NODES)        // per-relation (dst,mask) buckets
#define SCAN_TOTAL (3 * SCAN_N)     // 1,200,000
#define SCAN_CHUNK 2048             // elems per scan block (256 thr x 8)
#define SCAN_BLOCKS 586             // ceil(1.2M / 2048)
#define SCAN_PAD (SCAN_BLOCKS * SCAN_CHUNK)  // 1,200,128 (pad zeros)

typedef _Float16 f16x8 __attribute__((ext_vector_type(8)));
typedef _Float16 f16x4 __attribute__((ext_vector_type(4)));
typedef float f32x4 __attribute__((ext_vector_type(4)));

#define MFMA_F16(a, b, c) __builtin_amdgcn_mfma_f32_16x16x32_f16((a), (b), (c), 0, 0, 0)

#define CONV_BLOCKS 12500   // N*D/4/256
#define COUNT_BLOCKS 9375   // 3*E/256
#define PREPW_BLOCKS 768    // 3*4*16384/256

// ---- merged prep: conv_x | bucket-count | weight fp16 (disjoint block ranges)
__global__ __launch_bounds__(256) void prep_all(
    const float* __restrict__ x, _Float16* __restrict__ h,
    const int* __restrict__ ei0, const int* __restrict__ ei1, const int* __restrict__ ei2,
    const int* __restrict__ em0, const int* __restrict__ em1, const int* __restrict__ em2,
    int* __restrict__ cnt2, const float* __restrict__ W_l, const float* __restrict__ W_r,
    const float* __restrict__ b_l, _Float16* __restrict__ whi, float* __restrict__ bsum) {
    int b = blockIdx.x;
    int tid = threadIdx.x;
    if (b < CONV_BLOCKS) {
        int idx = b * 256 + tid;
        float4 v = reinterpret_cast<const float4*>(x)[idx];
        f16x4 o = {(_Float16)v.x, (_Float16)v.y, (_Float16)v.z, (_Float16)v.w};
        reinterpret_cast<f16x4*>(h)[idx] = o;
    } else if (b < CONV_BLOCKS + COUNT_BLOCKS) {
        int e = (b - CONV_BLOCKS) * 256 + tid;  // [0, 2.4M); r uniform per block
        int r = e / N_EDGES;
        int el = e - r * N_EDGES;
        const int* ei = (r == 0) ? ei0 : (r == 1) ? ei1 : ei2;
        const int* em = (r == 0) ? em0 : (r == 1) ? em1 : em2;
        int dst = ei[N_EDGES + el];
        int m = em[el];
        atomicAdd(&cnt2[(size_t)r * SCAN_N + dst * 4 + m], 1);
    } else {
        int idx = (b - CONV_BLOCKS - COUNT_BLOCKS) * 256 + tid;
        if (idx < 3 * 4 * 16384) {
            int i = idx / (4 * 16384);
            int rem = idx % (4 * 16384);
            int slot = rem / 16384;
            int ok = rem % 16384;
            float v;
            if (slot < 3) {
                v = W_l[(size_t)(i * 3 + slot) * 16384 + ok];
            } else {
                const float* base = W_r + (size_t)i * 3 * 16384;
                v = base[ok] + base[16384 + ok] + base[2 * 16384 + ok];
            }
            whi[idx] = (_Float16)v;
        }
        if (idx < 3 * 128) {
            int i = idx / 128, o = idx % 128;
            const float* bb = b_l + (size_t)i * 3 * 128;
            bsum[idx] = bb[o] + bb[128 + o] + bb[256 + o];
        }
    }
}

// ---- device-wide scan, pass 1: per-block sums (block = 2048 elems)
__global__ __launch_bounds__(256) void scan_part(const int* __restrict__ cnt2,
                                                 int* __restrict__ bsums) {
    int tid = threadIdx.x;
    size_t base = (size_t)blockIdx.x * SCAN_CHUNK + tid * 8;
    int4 v0 = *reinterpret_cast<const int4*>(cnt2 + base);
    int4 v1 = *reinterpret_cast<const int4*>(cnt2 + base + 4);
    int s = v0.x + v0.y + v0.z + v0.w + v1.x + v1.y + v1.z + v1.w;
    __shared__ int red[256];
    red[tid] = s;
    __syncthreads();
    for (int off = 128; off > 0; off >>= 1) {
        if (tid < off) red[tid] += red[tid + off];
        __syncthreads();
    }
    if (tid == 0) bsums[blockIdx.x] = red[0];
}

// ---- pass 2: exclusive scan of the 586 block sums (in place), one block
__global__ __launch_bounds__(1024) void scan_tops(int* __restrict__ bsums) {
    __shared__ int s[1024];
    int tid = threadIdx.x;
    int v = (tid < SCAN_BLOCKS) ? bsums[tid] : 0;
    s[tid] = v;
    __syncthreads();
    for (int off = 1; off < 1024; off <<= 1) {
        int x = s[tid];
        int add = (tid >= off) ? s[tid - off] : 0;
        __syncthreads();
        s[tid] = x + add;
        __syncthreads();
    }
    if (tid < SCAN_BLOCKS) bsums[tid] = s[tid] - v;  // exclusive
}

// ---- pass 3: per-block exclusive scan + offset -> bnd (global positions)
__global__ __launch_bounds__(256) void scan_out(const int* __restrict__ cnt2,
                                                const int* __restrict__ bsums,
                                                int* __restrict__ bnd) {
    int tid = threadIdx.x;
    size_t base = (size_t)blockIdx.x * SCAN_CHUNK + tid * 8;
    int4 v0 = *reinterpret_cast<const int4*>(cnt2 + base);
    int4 v1 = *reinterpret_cast<const int4*>(cnt2 + base + 4);
    int l[8] = {v0.x, v0.y, v0.z, v0.w, v1.x, v1.y, v1.z, v1.w};
    int ts = l[0] + l[1] + l[2] + l[3] + l[4] + l[5] + l[6] + l[7];
    __shared__ int s[256];
    s[tid] = ts;
    __syncthreads();
    for (int off = 1; off < 256; off <<= 1) {
        int x = s[tid];
        int add = (tid >= off) ? s[tid - off] : 0;
        __syncthreads();
        s[tid] = x + add;
        __syncthreads();
    }
    int run = bsums[blockIdx.x] + s[tid] - ts;  // exclusive offset for this thread
    int o[8];
#pragma unroll
    for (int j = 0; j < 8; j++) {
        o[j] = run;
        run += l[j];
    }
    int4 o0 = {o[0], o[1], o[2], o[3]};
    int4 o1 = {o[4], o[5], o[6], o[7]};
    *reinterpret_cast<int4*>(bnd + base) = o0;
    *reinterpret_cast<int4*>(bnd + base + 4) = o1;
}

// ---- fill: packed[pos] = src*D at global scan positions, bucketed by (rel,dst,mask)
__global__ __launch_bounds__(256) void fill3(
    const int* __restrict__ ei0, const int* __restrict__ ei1, const int* __restrict__ ei2,
    const int* __restrict__ em0, const int* __restrict__ em1, const int* __restrict__ em2,
    const int* __restrict__ bnd, int* __restrict__ fill2, int* __restrict__ packed) {
    int e = blockIdx.x * 256 + threadIdx.x;  // [0, 2.4M)
    int r = e / N_EDGES;
    int el = e - r * N_EDGES;
    const int* ei = (r == 0) ? ei0 : (r == 1) ? ei1 : ei2;
    const int* em = (r == 0) ? em0 : (r == 1) ? em1 : em2;
    int dst = ei[N_EDGES + el];
    int src = ei[el];
    int m = em[el];
    int gbk = r * SCAN_N + dst * 4 + m;
    int pos = bnd[gbk] + atomicAdd(&fill2[gbk], 1);
    packed[pos] = src * D;  // premultiplied row offset (elements)
}

// ---- fused layer: validity-skipped gather (R12 loop) + MFMA GEMM (single fp16 W)
// block = 256 thr (4 waves) = 32 dst rows x 128 cols; reads h_in, writes h_out/d_out.
__global__ __launch_bounds__(256, 8) void fused_layer(
    const _Float16* __restrict__ h_in, const int* __restrict__ bnd,
    const int* __restrict__ packed, const _Float16* __restrict__ Whi,
    const float* __restrict__ bias, const int* __restrict__ node_mask, int layer,
    _Float16* __restrict__ h_out, float* __restrict__ out_f32) {
    __shared__ __align__(16) _Float16 smean[3][32][136];  // pitch 272B: aligned, 2-way banks
    int tid = threadIdx.x;
    int wid = tid >> 6;
    int lane = tid & 63;
    int row0 = blockIdx.x * 32;

    // ---- block-level early-out: node_mask sorted; if first row invalid, all 32 are.
    if (node_mask[row0] > layer) {
        if (out_f32) {
            f32x4 z = {0.f, 0.f, 0.f, 0.f};
            f32x4* o = reinterpret_cast<f32x4*>(out_f32 + (size_t)row0 * D);
#pragma unroll
            for (int k = 0; k < 4; k++) o[tid + k * 256] = z;
        } else {
            f16x8 z = (f16x8)(_Float16)0;
            f16x8* o = reinterpret_cast<f16x8*>(h_out + (size_t)row0 * D);
#pragma unroll
            for (int k = 0; k < 2; k++) o[tid + k * 256] = z;
        }
        return;
    }

    int g = lane >> 4;  // task group 0..3
    int l = lane & 15;  // lane in group: owns cols l*8..l*8+7

    // ---- phase 1: 96 (rel,node) tasks; wave runs 4 concurrent groups x 6 iters.
    // Per 4-edge chunk: ONE aligned int4 index load (group-uniform) + 4 independent
    // row loads + 4x4 v_pk_add_f16 (proven-best R12 inner loop).
    const _Float16* hbase = h_in + l * 8;
#pragma unroll 1
    for (int it = 0; it < 6; it++) {
        int t = wid * 24 + it * 4 + g;
        int r = t >> 5;
        int n = t & 31;
        if (node_mask[row0 + n] > layer) continue;  // output row forced 0; skip gather
        const int* B = bnd + (size_t)r * SCAN_N + (row0 + n) * 4;
        int beg = B[0];
        int end = B[layer + 1];  // prefix: all edges with mask <= layer
        int deg = end - beg;
        f16x8 acc = (f16x8)(_Float16)0;
#pragma unroll 1
        for (int e4 = beg & ~3; e4 < end; e4 += 4) {
            int4 s4 = *reinterpret_cast<const int4*>(packed + e4);  // 16B-aligned, uniform in group
            if (e4 >= beg && e4 + 4 <= end) {  // interior chunk: all 4 valid (uniform branch)
                f16x8 v0 = *reinterpret_cast<const f16x8*>(hbase + (size_t)(uint)s4.x);
                f16x8 v1 = *reinterpret_cast<const f16x8*>(hbase + (size_t)(uint)s4.y);
                f16x8 v2 = *reinterpret_cast<const f16x8*>(hbase + (size_t)(uint)s4.z);
                f16x8 v3 = *reinterpret_cast<const f16x8*>(hbase + (size_t)(uint)s4.w);
                acc += v0;
                acc += v1;
                acc += v2;
                acc += v3;
            } else {  // boundary chunk (<=2 per task)
                int ss[4] = {s4.x, s4.y, s4.z, s4.w};
#pragma unroll
                for (int j = 0; j < 4; j++) {
                    int e = e4 + j;
                    if (e >= beg && e < end)
                        acc += *reinterpret_cast<const f16x8*>(hbase + (size_t)(uint)ss[j]);
                }
            }
        }
        float inv = 1.f / fmaxf((float)deg, 1.f);
        f16x8 mv;
#pragma unroll
        for (int k = 0; k < 8; k++) mv[k] = (_Float16)((float)acc[k] * inv);
        *reinterpret_cast<f16x8*>(&smean[r][n][l * 8]) = mv;
    }
    __syncthreads();

    // ---- phase 2: GEMM. wave -> 32 cols; 2x2 16x16 frags; K=128; single fp16 W term.
    // Skipped tasks leave garbage in their smean rows: harmless, since MFMA C-row r
    // depends only on A-row r, and invalid rows are forced to 0 in the epilogue.
    int colbase = wid * 32;
    int ln15 = lane & 15;
    int lg = lane >> 4;
    f32x4 acc[2][2] = {};

#pragma unroll
    for (int p = 0; p < 4; p++) {
        const _Float16* Whp = Whi + (size_t)p * 16384 + (size_t)colbase * D;
#pragma unroll
        for (int ks = 0; ks < 4; ks++) {
            int kof = ks * 32 + lg * 8;
            f16x8 a0f, a1f;
            if (p < 3) {
                a0f = *reinterpret_cast<const f16x8*>(&smean[p][ln15][kof]);
                a1f = *reinterpret_cast<const f16x8*>(&smean[p][16 + ln15][kof]);
            } else {
                a0f = *reinterpret_cast<const f16x8*>(h_in + (size_t)(row0 + ln15) * D + kof);
                a1f = *reinterpret_cast<const f16x8*>(h_in + (size_t)(row0 + 16 + ln15) * D + kof);
            }
            f16x8 bh0 = *reinterpret_cast<const f16x8*>(Whp + (size_t)ln15 * D + kof);
            f16x8 bh1 = *reinterpret_cast<const f16x8*>(Whp + (size_t)(16 + ln15) * D + kof);
            acc[0][0] = MFMA_F16(a0f, bh0, acc[0][0]);
            acc[0][1] = MFMA_F16(a0f, bh1, acc[0][1]);
            acc[1][0] = MFMA_F16(a1f, bh0, acc[1][0]);
            acc[1][1] = MFMA_F16(a1f, bh1, acc[1][1]);
        }
    }

    // ---- epilogue: row = row0 + r*16 + lg*4 + j, col = colbase + cc*16 + ln15.
#pragma unroll
    for (int r = 0; r < 2; r++)
#pragma unroll
        for (int j = 0; j < 4; j++) {
            int row = row0 + r * 16 + lg * 4 + j;
            bool valid = node_mask[row] <= layer;
#pragma unroll
            for (int cc = 0; cc < 2; cc++) {
                int col = colbase + cc * 16 + ln15;
                float v = acc[r][cc][j] + bias[col];
                v = valid ? fmaxf(v, 0.f) : 0.f;
                if (out_f32)
                    out_f32[(size_t)row * D + col] = v;
                else
                    h_out[(size_t)row * D + col] = (_Float16)v;
            }
        }
}

extern "C" void kernel_launch(void* const* d_in, const int* in_sizes, int n_in,
                              void* d_out, int out_size, void* d_ws, size_t ws_size,
                              hipStream_t stream) {
    const float* x = (const float*)d_in[0];
    const int* ei0 = (const int*)d_in[1];
    const int* ei1 = (const int*)d_in[2];
    const int* ei2 = (const int*)d_in[3];
    const int* node_mask = (const int*)d_in[4];
    const int* em0 = (const int*)d_in[5];
    const int* em1 = (const int*)d_in[6];
    const int* em2 = (const int*)d_in[7];
    const float* W_l = (const float*)d_in[8];
    const float* b_l = (const float*)d_in[9];
    const float* W_r = (const float*)d_in[10];

    // workspace (~75 MB)
    _Float16* hA = (_Float16*)d_ws;                            // N*D
    _Float16* hB = hA + (size_t)N_NODES * D;                   // N*D
    _Float16* whi = hB + (size_t)N_NODES * D;                  // 3*4*16384
    float* bsum = (float*)(whi + 3 * 4 * 16384);               // 3*128
    int* cnt2 = (int*)(bsum + 3 * 128);                        // SCAN_PAD (padded, zeroed)
    int* fill2 = cnt2 + SCAN_PAD;                              // SCAN_TOTAL
    int* bsums = fill2 + SCAN_TOTAL;                           // 640 (>= SCAN_BLOCKS)
    int* bnd = bsums + 640;                                    // SCAN_PAD
    int* packed = bnd + SCAN_PAD;                              // 3*E (global positions)

    // zero cnt2 (incl. padding) + fill2 in one contiguous memset
    hipMemsetAsync(cnt2, 0, (size_t)(SCAN_PAD + SCAN_TOTAL) * sizeof(int), stream);

    prep_all<<<CONV_BLOCKS + COUNT_BLOCKS + PREPW_BLOCKS, 256, 0, stream>>>(
        x, hA, ei0, ei1, ei2, em0, em1, em2, cnt2, W_l, W_r, b_l, whi, bsum);
    scan_part<<<SCAN_BLOCKS, 256, 0, stream>>>(cnt2, bsums);
    scan_tops<<<1, 1024, 0, stream>>>(bsums);
    scan_out<<<SCAN_BLOCKS, 256, 0, stream>>>(cnt2, bsums, bnd);
    fill3<<<COUNT_BLOCKS, 256, 0, stream>>>(ei0, ei1, ei2, em0, em1, em2, bnd, fill2, packed);

    _Float16* hin = hA;
    _Float16* hout = hB;
    for (int i = 0; i < 3; i++) {
        int layer = 3 - i;
        float* of = (i == 2) ? (float*)d_out : nullptr;
        fused_layer<<<N_NODES / 32, 256, 0, stream>>>(
            hin, bnd, packed, whi + (size_t)i * 4 * 16384,
            bsum + (size_t)i * 128, node_mask, layer, hout, of);
        _Float16* tmp = hin; hin = hout; hout = tmp;
    }
}